// Round 1
// baseline (290.795 us; speedup 1.0000x reference)
//
#include <hip/hip_runtime.h>
#include <cstdint>

#define NROWS 16384
#define FDIM 64
#define HDIM 128
#define ODIM 512
#define KDIM 8192   // FDIM * HDIM

#define BM 128
#define BN 128
#define BK 64

typedef short bf16x8 __attribute__((ext_vector_type(8)));
typedef float f32x4 __attribute__((ext_vector_type(4)));
typedef uint32_t u32x4 __attribute__((ext_vector_type(4)));

__device__ __forceinline__ uint16_t rne_bf16(float f) {
  uint32_t u = __builtin_bit_cast(uint32_t, f);
  u += 0x7fffu + ((u >> 16) & 1u);
  return (uint16_t)(u >> 16);
}

// ---- pre-kernel 1: W2 [K=8192][O=512] f32 -> W2T [O][K] bf16 (LDS tile transpose) ----
__global__ void prep_w2t(const float* __restrict__ W2, uint16_t* __restrict__ W2T) {
  __shared__ float tile[64][65];
  const int k0 = blockIdx.x * 64;
  const int o0 = blockIdx.y * 64;
  const int tx = threadIdx.x;  // 0..63
  const int ty = threadIdx.y;  // 0..7
#pragma unroll
  for (int j = 0; j < 8; ++j)
    tile[ty + 8 * j][tx] = W2[(size_t)(k0 + ty + 8 * j) * ODIM + o0 + tx];
  __syncthreads();
#pragma unroll
  for (int j = 0; j < 8; ++j)
    W2T[(size_t)(o0 + ty + 8 * j) * KDIM + k0 + tx] = rne_bf16(tile[tx][ty + 8 * j]);
}

// ---- pre-kernel 2: bf16 copies of W1/b1, and b2sum[o] = sum_f b2[f][o] ----
__global__ void prep_small(const float* __restrict__ W1, const float* __restrict__ b1,
                           const float* __restrict__ b2, uint16_t* __restrict__ w1bf,
                           uint16_t* __restrict__ b1bf, float* __restrict__ b2sum) {
  const int t = blockIdx.x * 256 + threadIdx.x;  // grid 32*256 = 8192 = F*H
  w1bf[t] = rne_bf16(W1[t]);
  b1bf[t] = rne_bf16(b1[t]);
  if (t < ODIM) {
    float s = 0.f;
#pragma unroll
    for (int f = 0; f < FDIM; ++f) s += b2[(size_t)f * ODIM + t];
    b2sum[t] = s;
  }
}

// ---- main fused kernel: A generated on the fly, B staged via global_load_lds ----
__global__ __launch_bounds__(256, 3) void mlp_gemm(
    const float* __restrict__ x, const uint16_t* __restrict__ w1bf,
    const uint16_t* __restrict__ b1bf, const uint16_t* __restrict__ W2T,
    const float* __restrict__ b2sum, float* __restrict__ out) {
  __shared__ __align__(16) uint16_t As[BM * BK];  // [m][kslot], XOR-swizzled cols
  __shared__ __align__(16) uint16_t Bs[BN * BK];  // [o][kslot], XOR-swizzled cols

  const int tid = threadIdx.x;
  const int bid = blockIdx.x;
  // o-block = bid&3: consecutive blocks hit different XCDs (round-robin), so each
  // XCD sees mostly one 2MB W2T slice -> L2-resident B.
  const int o0 = (bid & 3) * BN;
  const int m0 = (bid >> 2) * BM;

  const int wid = tid >> 6;
  const int lane = tid & 63;
  const int wm = (wid >> 1) * 64;
  const int wn = (wid & 1) * 64;
  const int q = lane >> 4;   // quad
  const int r = lane & 15;

  // A-staging roles: each lane -> rows {i*32+ar}, col-group ac (8 bf16)
  const int ar = tid >> 3;  // 0..31
  const int ac = tid & 7;   // 0..7
  // B-staging roles (global_load_lds: LDS = base + lane*16, no padding allowed;
  // swizzle the GLOBAL col-group instead so fragment reads are conflict-free)
  const int brow = lane >> 3;               // 0..7 within 8-row chunk
  const int bcg = (lane & 7) ^ brow;        // swizzled col group

  f32x4 acc[4][4];
#pragma unroll
  for (int i = 0; i < 4; ++i)
#pragma unroll
    for (int j = 0; j < 4; ++j) acc[i][j] = {0.f, 0.f, 0.f, 0.f};

  for (int f = 0; f < FDIM; ++f) {
    // x column for this feature, reused across both k-halves (L1-broadcast loads)
    float xv[4];
#pragma unroll
    for (int i = 0; i < 4; ++i)
      xv[i] = x[(size_t)(m0 + i * 32 + ar) * FDIM + f];

#pragma unroll
    for (int half = 0; half < 2; ++half) {
      const int kk = f * 2 + half;  // k-step, k0 = kk*64
      __syncthreads();  // previous tile fully consumed

      // -- stage B: 4 async 1KB chunks per wave --
#pragma unroll
      for (int j = 0; j < 4; ++j) {
        const int chunk = wid * 4 + j;  // 0..15, 8 rows each
        const uint16_t* gp =
            W2T + (size_t)(o0 + chunk * 8 + brow) * KDIM + kk * BK + bcg * 8;
        uint16_t* lp = &Bs[chunk * 512];  // wave-uniform base
        __builtin_amdgcn_global_load_lds(
            (const __attribute__((address_space(1))) uint32_t*)gp,
            (__attribute__((address_space(3))) uint32_t*)lp, 16, 0, 0);
      }

      // -- stage A: elu(x*w1+b1) -> bf16 (truncated), 32 elems/lane --
      const int hoff = half * 64 + ac * 8;
      u32x4 w1d = *(const u32x4*)(w1bf + f * HDIM + hoff);
      u32x4 b1d = *(const u32x4*)(b1bf + f * HDIM + hoff);
      float w1f[8], b1f[8];
#pragma unroll
      for (int p = 0; p < 4; ++p) {
        w1f[2 * p]     = __builtin_bit_cast(float, w1d[p] << 16);
        w1f[2 * p + 1] = __builtin_bit_cast(float, w1d[p] & 0xffff0000u);
        b1f[2 * p]     = __builtin_bit_cast(float, b1d[p] << 16);
        b1f[2 * p + 1] = __builtin_bit_cast(float, b1d[p] & 0xffff0000u);
      }
#pragma unroll
      for (int i = 0; i < 4; ++i) {
        const int m = i * 32 + ar;
        u32x4 ov;
#pragma unroll
        for (int p = 0; p < 4; ++p) {
          float plo = fmaf(xv[i], w1f[2 * p], b1f[2 * p]);
          float phi = fmaf(xv[i], w1f[2 * p + 1], b1f[2 * p + 1]);
          float elo = plo > 0.f ? plo : __expf(plo) - 1.f;
          float ehi = phi > 0.f ? phi : __expf(phi) - 1.f;
          // pack two truncated bf16: one v_perm_b32
          ov[p] = __builtin_amdgcn_perm(__builtin_bit_cast(uint32_t, ehi),
                                        __builtin_bit_cast(uint32_t, elo),
                                        0x07060302u);
        }
        *(u32x4*)&As[m * BK + ((ac ^ (m & 7)) * 8)] = ov;
      }
      __syncthreads();  // drains vmcnt (global_load_lds) + lgkm

      // -- compute: 2 k-chunks x 16 mfma --
#pragma unroll
      for (int kc = 0; kc < 2; ++kc) {
        bf16x8 af[4], bfr[4];
        const int cg = kc * 4 + q;
#pragma unroll
        for (int mt = 0; mt < 4; ++mt) {
          const int row = wm + mt * 16 + r;
          af[mt] = *(const bf16x8*)&As[row * BK + ((cg ^ (row & 7)) * 8)];
        }
#pragma unroll
        for (int nt = 0; nt < 4; ++nt) {
          const int row = wn + nt * 16 + r;
          bfr[nt] = *(const bf16x8*)&Bs[row * BK + ((cg ^ (row & 7)) * 8)];
        }
#pragma unroll
        for (int mt = 0; mt < 4; ++mt)
#pragma unroll
          for (int nt = 0; nt < 4; ++nt)
            acc[mt][nt] = __builtin_amdgcn_mfma_f32_16x16x32_bf16(
                af[mt], bfr[nt], acc[mt][nt], 0, 0, 0);
      }
    }
  }

  // ---- epilogue: + sum_f b2, * 1/sqrt(F) ----
  float bsv[4];
#pragma unroll
  for (int nt = 0; nt < 4; ++nt) bsv[nt] = b2sum[o0 + wn + nt * 16 + r];
#pragma unroll
  for (int mt = 0; mt < 4; ++mt)
#pragma unroll
    for (int nt = 0; nt < 4; ++nt)
#pragma unroll
      for (int v = 0; v < 4; ++v) {
        const int row = m0 + wm + mt * 16 + q * 4 + v;  // C/D: row=(lane>>4)*4+reg
        const int col = o0 + wn + nt * 16 + r;          //      col=lane&15
        out[(size_t)row * ODIM + col] = (acc[mt][nt][v] + bsv[nt]) * 0.125f;
      }
}

extern "C" void kernel_launch(void* const* d_in, const int* in_sizes, int n_in,
                              void* d_out, int out_size, void* d_ws, size_t ws_size,
                              hipStream_t stream) {
  const float* x  = (const float*)d_in[0];
  const float* W1 = (const float*)d_in[1];
  const float* b1 = (const float*)d_in[2];
  const float* W2 = (const float*)d_in[3];
  const float* b2 = (const float*)d_in[4];
  float* out = (float*)d_out;

  char* ws = (char*)d_ws;
  float*    b2sum = (float*)ws;                       // 2KB
  uint16_t* w1bf  = (uint16_t*)(ws + 4096);           // 16KB
  uint16_t* b1bf  = (uint16_t*)(ws + 4096 + 16384);   // 16KB
  uint16_t* W2T   = (uint16_t*)(ws + 65536);          // 8MB [O][K] bf16

  prep_w2t<<<dim3(KDIM / 64, ODIM / 64), dim3(64, 8), 0, stream>>>(W2, W2T);
  prep_small<<<32, 256, 0, stream>>>(W1, b1, b2, w1bf, b1bf, b2sum);
  mlp_gemm<<<(NROWS / BM) * (ODIM / BN), 256, 0, stream>>>(x, w1bf, b1bf, W2T,
                                                           b2sum, out);
}

// Round 2
// 254.773 us; speedup vs baseline: 1.1414x; 1.1414x over previous
//
#include <hip/hip_runtime.h>
#include <cstdint>

#define NROWS 16384
#define FDIM 64
#define HDIM 128
#define ODIM 512
#define KDIM 8192   // FDIM * HDIM

#define BM 64
#define BN 256
#define BK 64

typedef short bf16x8 __attribute__((ext_vector_type(8)));
typedef float f32x4 __attribute__((ext_vector_type(4)));
typedef uint32_t u32x4 __attribute__((ext_vector_type(4)));

__device__ __forceinline__ uint16_t rne_bf16(float f) {
  uint32_t u = __builtin_bit_cast(uint32_t, f);
  u += 0x7fffu + ((u >> 16) & 1u);
  return (uint16_t)(u >> 16);
}

// ---- pre-kernel 1: W2 [K=8192][O=512] f32 -> W2T [O][K] bf16 (LDS tile transpose) ----
__global__ void prep_w2t(const float* __restrict__ W2, uint16_t* __restrict__ W2T) {
  __shared__ float tile[64][65];
  const int k0 = blockIdx.x * 64;
  const int o0 = blockIdx.y * 64;
  const int tx = threadIdx.x;  // 0..63
  const int ty = threadIdx.y;  // 0..7
#pragma unroll
  for (int j = 0; j < 8; ++j)
    tile[ty + 8 * j][tx] = W2[(size_t)(k0 + ty + 8 * j) * ODIM + o0 + tx];
  __syncthreads();
#pragma unroll
  for (int j = 0; j < 8; ++j)
    W2T[(size_t)(o0 + ty + 8 * j) * KDIM + k0 + tx] = rne_bf16(tile[tx][ty + 8 * j]);
}

// ---- pre-kernel 2: bf16 copies of W1/b1, and b2sum[o] = sum_f b2[f][o] ----
__global__ void prep_small(const float* __restrict__ W1, const float* __restrict__ b1,
                           const float* __restrict__ b2, uint16_t* __restrict__ w1bf,
                           uint16_t* __restrict__ b1bf, float* __restrict__ b2sum) {
  const int t = blockIdx.x * 256 + threadIdx.x;  // grid 32*256 = 8192 = F*H
  w1bf[t] = rne_bf16(W1[t]);
  b1bf[t] = rne_bf16(b1[t]);
  if (t < ODIM) {
    float s = 0.f;
#pragma unroll
    for (int f = 0; f < FDIM; ++f) s += b2[(size_t)f * ODIM + t];
    b2sum[t] = s;
  }
}

// ---- main fused kernel: BM=64 x BN=256 tile, A generated on the fly ----
// elu recompute factor = #o-blocks = 2 (was 4 with BN=128); per-wave per-half
// MFMA stays 32 while elu elems/lane drops 32->16.
__global__ __launch_bounds__(256, 3) void mlp_gemm(
    const float* __restrict__ x, const uint16_t* __restrict__ w1bf,
    const uint16_t* __restrict__ b1bf, const uint16_t* __restrict__ W2T,
    const float* __restrict__ b2sum, float* __restrict__ out) {
  __shared__ __align__(16) uint16_t As[BM * BK];  // 8 KB, XOR-swizzled col groups
  __shared__ __align__(16) uint16_t Bs[BN * BK];  // 32 KB, XOR-swizzled col groups

  const int tid = threadIdx.x;
  const int bid = blockIdx.x;
  // consecutive bids alternate o-halves -> each XCD L2 holds both 32KB k-slices (trivial)
  const int o0 = (bid & 1) * BN;
  const int m0 = (bid >> 1) * BM;

  const int wid = tid >> 6;
  const int lane = tid & 63;
  const int wn = wid * 64;   // wave's n-slice; all waves span full BM=64 rows
  const int q = lane >> 4;   // quad
  const int r = lane & 15;

  // A-staging roles: lane -> rows {ar, ar+32}, col-group ac (8 bf16 each)
  const int ar = tid >> 3;  // 0..31
  const int ac = tid & 7;   // 0..7
  // B-staging roles (global_load_lds: LDS = wave-uniform base + lane*16;
  // swizzle the GLOBAL col-group so fragment reads stay conflict-free)
  const int brow = lane >> 3;           // 0..7 within an 8-row chunk
  const int bcg = (lane & 7) ^ brow;    // swizzled col group

  f32x4 acc[4][4];
#pragma unroll
  for (int i = 0; i < 4; ++i)
#pragma unroll
    for (int j = 0; j < 4; ++j) acc[i][j] = {0.f, 0.f, 0.f, 0.f};

  for (int f = 0; f < FDIM; ++f) {
    // x column for this feature, reused across both k-halves (L1-broadcast loads)
    float xv[2];
#pragma unroll
    for (int i = 0; i < 2; ++i)
      xv[i] = x[(size_t)(m0 + i * 32 + ar) * FDIM + f];

#pragma unroll
    for (int half = 0; half < 2; ++half) {
      const int kk = f * 2 + half;  // k-step index, k0 = kk*64
      __syncthreads();  // previous tile fully consumed

      // -- stage B: 8 async 1KB chunks per wave (32 chunks of 8 rows) --
#pragma unroll
      for (int j = 0; j < 8; ++j) {
        const int chunk = wid * 8 + j;  // 0..31
        const uint16_t* gp =
            W2T + (size_t)(o0 + chunk * 8 + brow) * KDIM + kk * BK + bcg * 8;
        uint16_t* lp = &Bs[chunk * 512];  // wave-uniform base
        __builtin_amdgcn_global_load_lds(
            (const __attribute__((address_space(1))) uint32_t*)gp,
            (__attribute__((address_space(3))) uint32_t*)lp, 16, 0, 0);
      }

      // -- stage A: elu(x*w1+b1) -> bf16 (truncated), 16 elems/lane --
      const int hoff = half * 64 + ac * 8;
      u32x4 w1d = *(const u32x4*)(w1bf + f * HDIM + hoff);
      u32x4 b1d = *(const u32x4*)(b1bf + f * HDIM + hoff);
      float w1f[8], b1f[8];
#pragma unroll
      for (int p = 0; p < 4; ++p) {
        w1f[2 * p]     = __builtin_bit_cast(float, w1d[p] << 16);
        w1f[2 * p + 1] = __builtin_bit_cast(float, w1d[p] & 0xffff0000u);
        b1f[2 * p]     = __builtin_bit_cast(float, b1d[p] << 16);
        b1f[2 * p + 1] = __builtin_bit_cast(float, b1d[p] & 0xffff0000u);
      }
#pragma unroll
      for (int i = 0; i < 2; ++i) {
        const int m = i * 32 + ar;
        u32x4 ov;
#pragma unroll
        for (int p = 0; p < 4; ++p) {
          float plo = fmaf(xv[i], w1f[2 * p], b1f[2 * p]);
          float phi = fmaf(xv[i], w1f[2 * p + 1], b1f[2 * p + 1]);
          float elo = plo > 0.f ? plo : __expf(plo) - 1.f;
          float ehi = phi > 0.f ? phi : __expf(phi) - 1.f;
          ov[p] = __builtin_amdgcn_perm(__builtin_bit_cast(uint32_t, ehi),
                                        __builtin_bit_cast(uint32_t, elo),
                                        0x07060302u);
        }
        *(u32x4*)&As[m * BK + ((ac ^ (m & 7)) * 8)] = ov;
      }
      __syncthreads();  // drains vmcnt (global_load_lds) + lgkm

      // -- compute: 2 k-chunks x 16 mfma --
#pragma unroll
      for (int kc = 0; kc < 2; ++kc) {
        bf16x8 af[4], bfr[4];
        const int cg = kc * 4 + q;
#pragma unroll
        for (int mt = 0; mt < 4; ++mt) {
          const int row = mt * 16 + r;  // m-range 0..63
          af[mt] = *(const bf16x8*)&As[row * BK + ((cg ^ (row & 7)) * 8)];
        }
#pragma unroll
        for (int nt = 0; nt < 4; ++nt) {
          const int row = wn + nt * 16 + r;
          bfr[nt] = *(const bf16x8*)&Bs[row * BK + ((cg ^ (row & 7)) * 8)];
        }
#pragma unroll
        for (int mt = 0; mt < 4; ++mt)
#pragma unroll
          for (int nt = 0; nt < 4; ++nt)
            acc[mt][nt] = __builtin_amdgcn_mfma_f32_16x16x32_bf16(
                af[mt], bfr[nt], acc[mt][nt], 0, 0, 0);
      }
    }
  }

  // ---- epilogue: + sum_f b2, * 1/sqrt(F) ----
  float bsv[4];
#pragma unroll
  for (int nt = 0; nt < 4; ++nt) bsv[nt] = b2sum[o0 + wn + nt * 16 + r];
#pragma unroll
  for (int mt = 0; mt < 4; ++mt)
#pragma unroll
    for (int nt = 0; nt < 4; ++nt)
#pragma unroll
      for (int v = 0; v < 4; ++v) {
        const int row = m0 + mt * 16 + q * 4 + v;  // C/D: row=(lane>>4)*4+reg
        const int col = o0 + wn + nt * 16 + r;     //      col=lane&15
        out[(size_t)row * ODIM + col] = (acc[mt][nt][v] + bsv[nt]) * 0.125f;
      }
}

extern "C" void kernel_launch(void* const* d_in, const int* in_sizes, int n_in,
                              void* d_out, int out_size, void* d_ws, size_t ws_size,
                              hipStream_t stream) {
  const float* x  = (const float*)d_in[0];
  const float* W1 = (const float*)d_in[1];
  const float* b1 = (const float*)d_in[2];
  const float* W2 = (const float*)d_in[3];
  const float* b2 = (const float*)d_in[4];
  float* out = (float*)d_out;

  char* ws = (char*)d_ws;
  float*    b2sum = (float*)ws;                       // 2KB
  uint16_t* w1bf  = (uint16_t*)(ws + 4096);           // 16KB
  uint16_t* b1bf  = (uint16_t*)(ws + 4096 + 16384);   // 16KB
  uint16_t* W2T   = (uint16_t*)(ws + 65536);          // 8MB [O][K] bf16

  prep_w2t<<<dim3(KDIM / 64, ODIM / 64), dim3(64, 8), 0, stream>>>(W2, W2T);
  prep_small<<<32, 256, 0, stream>>>(W1, b1, b2, w1bf, b1bf, b2sum);
  mlp_gemm<<<(NROWS / BM) * (ODIM / BN), 256, 0, stream>>>(x, w1bf, b1bf, W2T,
                                                           b2sum, out);
}